// Round 1
// baseline (1806.880 us; speedup 1.0000x reference)
//
#include <hip/hip_runtime.h>
#include <math.h>

#define SEQL 2048
#define NB   4
#define HID  4096
#define DM   128
#define DIN  256
#define DST  16
#define HD   64
#define NH   4
#define CONV_DIM 288
#define DPROJ 552
#define MROWS (SEQL*NB)      // 8192
#define TCH 64
#define NCHUNK (SEQL/TCH)    // 32

__device__ __forceinline__ float siluf(float v){ return v / (1.f + expf(-v)); }
__device__ __forceinline__ float geluf(float v){ return 0.5f*v*(1.f + erff(v*0.70710678118654752f)); }
__device__ __forceinline__ float wave_sum(float v){
    #pragma unroll
    for (int o = 32; o > 0; o >>= 1) v += __shfl_xor(v, o, 64);
    return v;
}

// ---------------- K1: down-proj (x (l,b,HID) -> xmid (b,l,DM)) + bias + exact GELU
__global__ __launch_bounds__(256) void k_down(const float* __restrict__ x,
    const float* __restrict__ w, const float* __restrict__ bias,
    float* __restrict__ out)
{
    __shared__ float As[32][33];    // [row][k]
    __shared__ float Ws[32][132];   // [k][j]
    const int tid = threadIdx.x;
    const int m0  = blockIdx.x * 32;
    const int tx  = tid & 15, ty = tid >> 4;
    float acc[2][8];
    #pragma unroll
    for (int r = 0; r < 2; ++r)
        #pragma unroll
        for (int c = 0; c < 8; ++c) acc[r][c] = 0.f;

    for (int k0 = 0; k0 < HID; k0 += 32) {
        for (int i = tid; i < 32*32; i += 256) {
            int row = i >> 5, kk = i & 31;
            int m = m0 + row, b = m >> 11, l = m & 2047;
            As[row][kk] = x[(size_t)(l*NB + b)*HID + k0 + kk];
        }
        for (int i = tid; i < 128*32; i += 256) {
            int j = i >> 5, kk = i & 31;
            Ws[kk][j] = w[(size_t)j*HID + k0 + kk];
        }
        __syncthreads();
        #pragma unroll
        for (int kk = 0; kk < 32; ++kk) {
            float a0 = As[ty*2+0][kk];
            float a1 = As[ty*2+1][kk];
            float bv[8];
            *(float4*)&bv[0] = *(const float4*)&Ws[kk][tx*8];
            *(float4*)&bv[4] = *(const float4*)&Ws[kk][tx*8+4];
            #pragma unroll
            for (int c = 0; c < 8; ++c) {
                acc[0][c] = fmaf(a0, bv[c], acc[0][c]);
                acc[1][c] = fmaf(a1, bv[c], acc[1][c]);
            }
        }
        __syncthreads();
    }
    #pragma unroll
    for (int r = 0; r < 2; ++r) {
        int m = m0 + ty*2 + r;
        #pragma unroll
        for (int cg = 0; cg < 2; ++cg) {
            int j0 = tx*8 + cg*4;
            float4 v;
            v.x = geluf(acc[r][cg*4+0] + bias[j0+0]);
            v.y = geluf(acc[r][cg*4+1] + bias[j0+1]);
            v.z = geluf(acc[r][cg*4+2] + bias[j0+2]);
            v.w = geluf(acc[r][cg*4+3] + bias[j0+3]);
            *(float4*)&out[(size_t)m*DM + j0] = v;
        }
    }
}

// ---------------- generic out = A(M x K) @ W(N x K)^T, A row stride == K
template<int K>
__global__ __launch_bounds__(256) void k_gemm_awt(const float* __restrict__ Am,
    const float* __restrict__ W, float* __restrict__ out, int N, int ostride)
{
    __shared__ float Ak[K][33];   // [k][row]
    const int tid = threadIdx.x;
    const int m0  = blockIdx.x * 32;
    for (int r = 0; r < 32; ++r)
        for (int k = tid; k < K; k += 256)
            Ak[k][r] = Am[(size_t)(m0 + r)*K + k];
    __syncthreads();
    const int row = tid & 31, ng = tid >> 5;
    for (int n = ng; n < N; n += 8) {
        const float* wr = W + (size_t)n*K;
        float acc = 0.f;
        #pragma unroll
        for (int k = 0; k < K; k += 4) {
            float4 w4 = *(const float4*)&wr[k];
            acc = fmaf(Ak[k+0][row], w4.x, acc);
            acc = fmaf(Ak[k+1][row], w4.y, acc);
            acc = fmaf(Ak[k+2][row], w4.z, acc);
            acc = fmaf(Ak[k+3][row], w4.w, acc);
        }
        out[(size_t)(m0 + row)*ostride + n] = acc;
    }
}

// ---------------- K3: causal depthwise conv7 + bias + silu
__global__ __launch_bounds__(256) void k_conv(const float* __restrict__ zx,
    const float* __restrict__ cw, const float* __restrict__ cb,
    float* __restrict__ xBC)
{
    int idx = blockIdx.x*256 + threadIdx.x;
    if (idx >= MROWS*CONV_DIM) return;
    int c = idx % CONV_DIM;
    int m = idx / CONV_DIM;
    int l = m & 2047, b = m >> 11;
    float acc = cb[c];
    #pragma unroll
    for (int k = 0; k < 7; ++k) {
        int l2 = l - 6 + k;
        if (l2 >= 0)
            acc = fmaf(zx[(size_t)(b*SEQL + l2)*DPROJ + DIN + c], cw[c*7 + k], acc);
    }
    xBC[(size_t)m*CONV_DIM + c] = siluf(acc);
}

// ---------------- K4a: chunk-local scan states (no outputs)
__global__ __launch_bounds__(64) void k_scan_state(const float* __restrict__ zx,
    const float* __restrict__ xBC, const float* __restrict__ dt_bias,
    const float* __restrict__ A_log, float* __restrict__ Sbuf, float* __restrict__ Pbuf)
{
    const int bid = blockIdx.x;
    const int c   = bid & (NCHUNK-1);
    const int h   = (bid >> 5) & (NH-1);
    const int b   = (bid >> 7) & 3;
    const int dir = bid >> 9;
    const int tid = threadIdx.x;
    __shared__ float dA_s[TCH], dt_s[TCH];
    __shared__ float Xs[TCH][HD];
    __shared__ float Bs[TCH][DST];
    {
        const int kk = tid;
        const int l = dir ? (SEQL-1 - (c*TCH + kk)) : (c*TCH + kk);
        float dtraw = zx[(size_t)(b*SEQL + l)*DPROJ + 544 + dir*NH + h] + dt_bias[h];
        float dt = dtraw > 20.f ? dtraw : log1pf(expf(dtraw));
        dt_s[kk] = dt;
        dA_s[kk] = expf(dt * (-expf(A_log[h])));
    }
    __syncthreads();
    for (int i = tid; i < TCH*HD; i += 64) {
        int k2 = i >> 6, p = i & 63;
        int l2 = dir ? (SEQL-1 - (c*TCH + k2)) : (c*TCH + k2);
        Xs[k2][p] = dt_s[k2] * xBC[(size_t)(b*SEQL + l2)*CONV_DIM + h*HD + p];
    }
    for (int i = tid; i < TCH*DST; i += 64) {
        int k2 = i >> 4, n = i & 15;
        int l2 = dir ? (SEQL-1 - (c*TCH + k2)) : (c*TCH + k2);
        Bs[k2][n] = xBC[(size_t)(b*SEQL + l2)*CONV_DIM + DIN + n];
    }
    __syncthreads();
    const int pg = tid >> 2, ng = tid & 3;
    float s[4][4];
    #pragma unroll
    for (int i = 0; i < 4; ++i)
        #pragma unroll
        for (int j = 0; j < 4; ++j) s[i][j] = 0.f;
    for (int k2 = 0; k2 < TCH; ++k2) {
        float dAv = dA_s[k2];
        float4 xv = *(const float4*)&Xs[k2][pg*4];
        float4 bv = *(const float4*)&Bs[k2][ng*4];
        float xa[4] = {xv.x, xv.y, xv.z, xv.w};
        float ba[4] = {bv.x, bv.y, bv.z, bv.w};
        #pragma unroll
        for (int i = 0; i < 4; ++i)
            #pragma unroll
            for (int j = 0; j < 4; ++j)
                s[i][j] = fmaf(dAv, s[i][j], xa[i]*ba[j]);
    }
    size_t sb = (size_t)bid * 1024;
    #pragma unroll
    for (int i = 0; i < 4; ++i) {
        float4 v = {s[i][0], s[i][1], s[i][2], s[i][3]};
        *(float4*)&Sbuf[sb + (size_t)((pg*4+i)*16 + ng*4)] = v;
    }
    if (tid == 0) {
        float P = 1.f;
        for (int k2 = 0; k2 < TCH; ++k2) P *= dA_s[k2];
        Pbuf[bid] = P;
    }
}

// ---------------- K4b: sequential combine of chunk states (32 steps)
__global__ __launch_bounds__(1024) void k_scan_combine(const float* __restrict__ Sbuf,
    const float* __restrict__ Pbuf, float* __restrict__ Hbuf)
{
    const int t = threadIdx.x;
    const size_t base = (size_t)blockIdx.x * NCHUNK;
    float carry = 0.f;
    for (int c = 0; c < NCHUNK; ++c) {
        size_t cb = (base + c) * 1024;
        Hbuf[cb + t] = carry;
        carry = fmaf(Pbuf[base + c], carry, Sbuf[cb + t]);
    }
}

// ---------------- K4c: replay chunks with correct init state, emit y
__global__ __launch_bounds__(64) void k_scan_out(const float* __restrict__ zx,
    const float* __restrict__ xBC, const float* __restrict__ dt_bias,
    const float* __restrict__ A_log, const float* __restrict__ Hbuf,
    float* __restrict__ yfw, float* __restrict__ ybw)
{
    const int bid = blockIdx.x;
    const int c   = bid & (NCHUNK-1);
    const int h   = (bid >> 5) & (NH-1);
    const int b   = (bid >> 7) & 3;
    const int dir = bid >> 9;
    const int tid = threadIdx.x;
    __shared__ float dA_s[TCH], dt_s[TCH];
    __shared__ float Xs[TCH][HD];
    __shared__ float Bs[TCH][DST];
    __shared__ float Cs[TCH][DST];
    {
        const int kk = tid;
        const int l = dir ? (SEQL-1 - (c*TCH + kk)) : (c*TCH + kk);
        float dtraw = zx[(size_t)(b*SEQL + l)*DPROJ + 544 + dir*NH + h] + dt_bias[h];
        float dt = dtraw > 20.f ? dtraw : log1pf(expf(dtraw));
        dt_s[kk] = dt;
        dA_s[kk] = expf(dt * (-expf(A_log[h])));
    }
    __syncthreads();
    for (int i = tid; i < TCH*HD; i += 64) {
        int k2 = i >> 6, p = i & 63;
        int l2 = dir ? (SEQL-1 - (c*TCH + k2)) : (c*TCH + k2);
        Xs[k2][p] = dt_s[k2] * xBC[(size_t)(b*SEQL + l2)*CONV_DIM + h*HD + p];
    }
    for (int i = tid; i < TCH*DST; i += 64) {
        int k2 = i >> 4, n = i & 15;
        int l2 = dir ? (SEQL-1 - (c*TCH + k2)) : (c*TCH + k2);
        Bs[k2][n] = xBC[(size_t)(b*SEQL + l2)*CONV_DIM + DIN + n];
        Cs[k2][n] = xBC[(size_t)(b*SEQL + l2)*CONV_DIM + DIN + DST + n];
    }
    __syncthreads();
    const int pg = tid >> 2, ng = tid & 3;
    float s[4][4];
    size_t hb = (size_t)bid * 1024;
    #pragma unroll
    for (int i = 0; i < 4; ++i) {
        float4 v = *(const float4*)&Hbuf[hb + (size_t)((pg*4+i)*16 + ng*4)];
        s[i][0] = v.x; s[i][1] = v.y; s[i][2] = v.z; s[i][3] = v.w;
    }
    float* yout = dir ? ybw : yfw;
    for (int k2 = 0; k2 < TCH; ++k2) {
        float dAv = dA_s[k2];
        float4 xv = *(const float4*)&Xs[k2][pg*4];
        float4 bv = *(const float4*)&Bs[k2][ng*4];
        float4 cv = *(const float4*)&Cs[k2][ng*4];
        float xa[4] = {xv.x, xv.y, xv.z, xv.w};
        float ba[4] = {bv.x, bv.y, bv.z, bv.w};
        float ca[4] = {cv.x, cv.y, cv.z, cv.w};
        float y[4];
        #pragma unroll
        for (int i = 0; i < 4; ++i) {
            #pragma unroll
            for (int j = 0; j < 4; ++j)
                s[i][j] = fmaf(dAv, s[i][j], xa[i]*ba[j]);
            y[i] = s[i][0]*ca[0] + s[i][1]*ca[1] + s[i][2]*ca[2] + s[i][3]*ca[3];
        }
        #pragma unroll
        for (int i = 0; i < 4; ++i) {
            y[i] += __shfl_xor(y[i], 1, 64);
            y[i] += __shfl_xor(y[i], 2, 64);
        }
        if (ng == 0) {
            int l2 = dir ? (SEQL-1 - (c*TCH + k2)) : (c*TCH + k2);
            float4 v = {y[0], y[1], y[2], y[3]};
            *(float4*)&yout[(size_t)(b*SEQL + l2)*DIN + h*HD + pg*4] = v;
        }
    }
}

// ---------------- K5: shift-combine + D-skip + gate + RMSNorm -> yn
__global__ __launch_bounds__(256) void k_epi(const float* __restrict__ zx,
    const float* __restrict__ xBC, const float* __restrict__ yfw,
    const float* __restrict__ ybw, const float* __restrict__ fcD_w,
    const float* __restrict__ Dv, const float* __restrict__ norm_w,
    float* __restrict__ yn_out)
{
    const int m = blockIdx.x;
    const int l = m & (SEQL-1);
    const int d = threadIdx.x;
    const int lane = d & 63, wave = d >> 6;
    __shared__ float red[4][4];
    __shared__ float redq[4];
    float xs = xBC[(size_t)m*CONV_DIM + d];
    float yv = 0.f;
    if (l > 0)       yv += yfw[(size_t)(m-1)*DIN + d];
    if (l < SEQL-1)  yv += ybw[(size_t)(m+1)*DIN + d];
    float p0 = wave_sum(xs * fcD_w[0*DIN + d]);
    float p1 = wave_sum(xs * fcD_w[1*DIN + d]);
    float p2 = wave_sum(xs * fcD_w[2*DIN + d]);
    float p3 = wave_sum(xs * fcD_w[3*DIN + d]);
    if (lane == 0) { red[wave][0]=p0; red[wave][1]=p1; red[wave][2]=p2; red[wave][3]=p3; }
    __syncthreads();
    const int h = d >> 6;
    float scal = red[0][h] + red[1][h] + red[2][h] + red[3][h] + Dv[h];
    yv = fmaf(xs, scal, yv);
    float z  = zx[(size_t)m*DPROJ + d];
    float yz = yv * siluf(z);
    float q = wave_sum(yz*yz);
    if (lane == 0) redq[wave] = q;
    __syncthreads();
    float ms = (redq[0] + redq[1] + redq[2] + redq[3]) * (1.f/DIN);
    float r = rsqrtf(ms + 1e-5f);
    yn_out[(size_t)m*DIN + d] = yz * r * norm_w[d];
}

// ---------------- K6: combine + up-proj + bias + transpose + residual
__global__ __launch_bounds__(128) void k_up(const float* __restrict__ xmid,
    const float* __restrict__ h2, const float* __restrict__ w_up,
    const float* __restrict__ b_up, const float* __restrict__ gate1,
    const float* __restrict__ x, float* __restrict__ out)
{
    __shared__ float Hs[128][36];   // [k][row], rows 0..31
    __shared__ float Ws[128][68];   // [k][n],  n 0..63
    const int tid = threadIdx.x;    // 128 threads
    const int m0  = blockIdx.x * 32;
    const int n0  = blockIdx.y * 64;
    const float alpha = 1.f / (1.f + expf(-gate1[0]));
    for (int i = tid; i < 32*128; i += 128) {
        int row = i >> 7, k = i & 127;
        size_t idx = (size_t)(m0 + row)*DM + k;
        Hs[k][row] = (1.f + alpha)*xmid[idx] + (1.f - alpha)*h2[idx];
    }
    for (int i = tid; i < 64*128; i += 128) {
        int n = i >> 7, k = i & 127;
        Ws[k][n] = w_up[(size_t)(n0 + n)*DM + k];
    }
    __syncthreads();
    const int tx = tid & 15, ty = tid >> 4;   // 16 col-groups x 8 row-groups
    float acc[4][4];
    #pragma unroll
    for (int i = 0; i < 4; ++i)
        #pragma unroll
        for (int j = 0; j < 4; ++j) acc[i][j] = 0.f;
    #pragma unroll 4
    for (int k = 0; k < 128; ++k) {
        float a0 = Hs[k][ty*4+0];
        float a1 = Hs[k][ty*4+1];
        float a2 = Hs[k][ty*4+2];
        float a3 = Hs[k][ty*4+3];
        float4 wv = *(const float4*)&Ws[k][tx*4];
        float wa[4] = {wv.x, wv.y, wv.z, wv.w};
        #pragma unroll
        for (int j = 0; j < 4; ++j) {
            acc[0][j] = fmaf(a0, wa[j], acc[0][j]);
            acc[1][j] = fmaf(a1, wa[j], acc[1][j]);
            acc[2][j] = fmaf(a2, wa[j], acc[2][j]);
            acc[3][j] = fmaf(a3, wa[j], acc[3][j]);
        }
    }
    const int col = n0 + tx*4;
    float4 bu = *(const float4*)&b_up[col];
    #pragma unroll
    for (int i = 0; i < 4; ++i) {
        int m = m0 + ty*4 + i;
        int b = m >> 11, l = m & 2047;
        size_t oi = (size_t)(l*NB + b)*HID + col;
        float4 xr = *(const float4*)&x[oi];
        float4 v;
        v.x = acc[i][0] + bu.x + xr.x;
        v.y = acc[i][1] + bu.y + xr.y;
        v.z = acc[i][2] + bu.z + xr.z;
        v.w = acc[i][3] + bu.w + xr.w;
        *(float4*)&out[oi] = v;
    }
}

extern "C" void kernel_launch(void* const* d_in, const int* in_sizes, int n_in,
                              void* d_out, int out_size, void* d_ws, size_t ws_size,
                              hipStream_t stream)
{
    const float* x       = (const float*)d_in[0];
    const float* w_down  = (const float*)d_in[1];
    const float* b_down  = (const float*)d_in[2];
    const float* w_up    = (const float*)d_in[3];
    const float* b_up    = (const float*)d_in[4];
    const float* gate1   = (const float*)d_in[5];
    const float* in_w    = (const float*)d_in[6];
    const float* conv_w  = (const float*)d_in[7];
    const float* conv_b  = (const float*)d_in[8];
    const float* dt_bias = (const float*)d_in[9];
    const float* A_log   = (const float*)d_in[10];
    const float* Dv      = (const float*)d_in[11];
    const float* fcD_w   = (const float*)d_in[12];
    const float* norm_w  = (const float*)d_in[13];
    const float* out_w   = (const float*)d_in[14];
    float* out = (float*)d_out;
    float* ws  = (float*)d_ws;

    // workspace layout (floats); total ~65.3 MB
    float* xmid = ws;                                  // M*128
    float* h1   = xmid + (size_t)MROWS*DM;             // M*128
    float* h2   = h1   + (size_t)MROWS*DM;             // M*128
    float* zx   = h2   + (size_t)MROWS*DM;             // M*552
    float* xBC  = zx   + (size_t)MROWS*DPROJ;          // M*288
    float* yfw  = xBC  + (size_t)MROWS*CONV_DIM;       // M*256
    float* ybw  = yfw  + (size_t)MROWS*DIN;            // M*256
    float* Sbuf = ybw  + (size_t)MROWS*DIN;            // 1024*1024
    float* Pbuf = Sbuf + (size_t)1024*1024;            // 1024
    float* Hbuf = Pbuf + 1024;                         // 1024*1024
    float* ynbuf = Sbuf;  // overlay: yn only needed after scan passes finish

    k_down<<<MROWS/32, 256, 0, stream>>>(x, w_down, b_down, xmid);

    for (int pass = 0; pass < 2; ++pass) {
        const float* u = pass ? h1 : xmid;
        float* hout    = pass ? h2 : h1;
        k_gemm_awt<128><<<MROWS/32, 256, 0, stream>>>(u, in_w, zx, DPROJ, DPROJ);
        k_conv<<<(MROWS*CONV_DIM)/256, 256, 0, stream>>>(zx, conv_w, conv_b, xBC);
        k_scan_state<<<1024, 64, 0, stream>>>(zx, xBC, dt_bias, A_log, Sbuf, Pbuf);
        k_scan_combine<<<32, 1024, 0, stream>>>(Sbuf, Pbuf, Hbuf);
        k_scan_out<<<1024, 64, 0, stream>>>(zx, xBC, dt_bias, A_log, Hbuf, yfw, ybw);
        k_epi<<<MROWS, 256, 0, stream>>>(zx, xBC, yfw, ybw, fcD_w, Dv, norm_w, ynbuf);
        k_gemm_awt<256><<<MROWS/32, 256, 0, stream>>>(ynbuf, out_w, hout, DM, DM);
    }

    dim3 gup(MROWS/32, HID/64);
    k_up<<<gup, 128, 0, stream>>>(xmid, h2, w_up, b_up, gate1, x, out);
}

// Round 2
// 528.491 us; speedup vs baseline: 3.4189x; 3.4189x over previous
//
#include <hip/hip_runtime.h>
#include <hip/hip_bf16.h>
#include <math.h>

#define SEQL 2048
#define NB   4
#define HID  4096
#define DM   128
#define DIN  256
#define DST  16
#define HD   64
#define NH   4
#define CONV_DIM 288
#define DPROJ 552
#define MROWS (SEQL*NB)      // 8192
#define TCH 64
#define NCHUNK (SEQL/TCH)    // 32

typedef __attribute__((ext_vector_type(8))) short short8;
typedef __attribute__((ext_vector_type(4))) float f32x4;

__device__ __forceinline__ float siluf(float v){ return v / (1.f + expf(-v)); }
__device__ __forceinline__ float geluf(float v){ return 0.5f*v*(1.f + erff(v*0.70710678118654752f)); }
__device__ __forceinline__ float wave_sum(float v){
    #pragma unroll
    for (int o = 32; o > 0; o >>= 1) v += __shfl_xor(v, o, 64);
    return v;
}
__device__ __forceinline__ unsigned bfpack2(float a, float b){
    __hip_bfloat162 v = __float22bfloat162_rn(make_float2(a, b));
    return *reinterpret_cast<unsigned*>(&v);
}

// ---------------- prep: convert weights to bf16 (in_w padded 552->560 rows)
__global__ __launch_bounds__(256) void k_prep_w(const float* __restrict__ w_down,
    const float* __restrict__ w_up, const float* __restrict__ in_w,
    const float* __restrict__ out_w,
    __hip_bfloat16* __restrict__ wd, __hip_bfloat16* __restrict__ wu,
    __hip_bfloat16* __restrict__ wi, __hip_bfloat16* __restrict__ wo)
{
    int idx = blockIdx.x*256 + threadIdx.x;
    if (idx < 524288) { wd[idx] = __float2bfloat16(w_down[idx]); return; }
    idx -= 524288;
    if (idx < 524288) { wu[idx] = __float2bfloat16(w_up[idx]); return; }
    idx -= 524288;
    if (idx < 71680) { wi[idx] = (idx < 552*128) ? __float2bfloat16(in_w[idx]) : __float2bfloat16(0.f); return; }
    idx -= 71680;
    if (idx < 32768) { wo[idx] = __float2bfloat16(out_w[idx]); }
}

// ---------------- K1: down-proj MFMA, split-K x2, partial out
__global__ __launch_bounds__(256) void k_down_mfma(const float* __restrict__ x,
    const __hip_bfloat16* __restrict__ wbf, float* __restrict__ partial)
{
    __shared__ __align__(16) short Abuf[64][72];
    __shared__ __align__(16) short Wbuf[128][72];
    const int tid = threadIdx.x;
    const int m0 = blockIdx.x * 64;
    const int ks = blockIdx.y;
    const int b  = m0 >> 11, l0 = m0 & 2047;
    const int lane = tid & 63, wv = tid >> 6;
    const int fr = lane & 15, q = lane >> 4;
    f32x4 acc[8];
    #pragma unroll
    for (int i = 0; i < 8; ++i) acc[i] = (f32x4){0.f,0.f,0.f,0.f};

    const int arow = tid >> 2, aseg = tid & 3;   // A: 4 thr/row, 16 floats
    const int wrow = tid >> 1, wseg = tid & 1;   // W: 2 thr/row, 32 shorts

    for (int k0 = ks*2048; k0 < ks*2048 + 2048; k0 += 64) {
        const float4* ap = (const float4*)(x + (size_t)((l0 + arow)*NB + b)*HID + k0 + aseg*16);
        float4 f0 = ap[0], f1 = ap[1], f2 = ap[2], f3 = ap[3];
        const uint4* wp = (const uint4*)(wbf + (size_t)wrow*HID + k0 + wseg*32);
        uint4 w0 = wp[0], w1 = wp[1], w2 = wp[2], w3 = wp[3];
        uint4 pk0, pk1;
        pk0.x = bfpack2(f0.x,f0.y); pk0.y = bfpack2(f0.z,f0.w);
        pk0.z = bfpack2(f1.x,f1.y); pk0.w = bfpack2(f1.z,f1.w);
        pk1.x = bfpack2(f2.x,f2.y); pk1.y = bfpack2(f2.z,f2.w);
        pk1.z = bfpack2(f3.x,f3.y); pk1.w = bfpack2(f3.z,f3.w);
        uint4* adst = (uint4*)&Abuf[arow][aseg*16];
        adst[0] = pk0; adst[1] = pk1;
        uint4* wdst = (uint4*)&Wbuf[wrow][wseg*32];
        wdst[0] = w0; wdst[1] = w1; wdst[2] = w2; wdst[3] = w3;
        __syncthreads();
        #pragma unroll
        for (int kh = 0; kh < 2; ++kh) {
            short8 af = *reinterpret_cast<const short8*>(&Abuf[wv*16 + fr][kh*32 + q*8]);
            #pragma unroll
            for (int ns = 0; ns < 8; ++ns) {
                short8 bf = *reinterpret_cast<const short8*>(&Wbuf[ns*16 + fr][kh*32 + q*8]);
                acc[ns] = __builtin_amdgcn_mfma_f32_16x16x32_bf16(af, bf, acc[ns], 0, 0, 0);
            }
        }
        __syncthreads();
    }
    #pragma unroll
    for (int ns = 0; ns < 8; ++ns)
        #pragma unroll
        for (int r = 0; r < 4; ++r)
            partial[((size_t)ks*MROWS + m0 + wv*16 + q*4 + r)*DM + ns*16 + fr] = acc[ns][r];
}

// ---------------- K1b: partial reduce + bias + GELU -> xmid fp32 + u_bf
__global__ __launch_bounds__(256) void k_down_fix(const float* __restrict__ partial,
    const float* __restrict__ bias, float* __restrict__ xmid,
    __hip_bfloat16* __restrict__ ubf)
{
    size_t i4 = ((size_t)blockIdx.x*256 + threadIdx.x)*4;
    int n = (int)(i4 & (DM-1));
    float4 p0 = *(const float4*)&partial[i4];
    float4 p1 = *(const float4*)&partial[(size_t)MROWS*DM + i4];
    float4 bv = *(const float4*)&bias[n];
    float4 v;
    v.x = geluf(p0.x + p1.x + bv.x);
    v.y = geluf(p0.y + p1.y + bv.y);
    v.z = geluf(p0.z + p1.z + bv.z);
    v.w = geluf(p0.w + p1.w + bv.w);
    *(float4*)&xmid[i4] = v;
    uint2 pk; pk.x = bfpack2(v.x, v.y); pk.y = bfpack2(v.z, v.w);
    *(uint2*)&ubf[i4] = pk;
}

// ---------------- in-proj MFMA: zx = u(bf16) @ in_w(bf16)^T  (N padded to 560)
__global__ __launch_bounds__(256) void k_proj_in(const __hip_bfloat16* __restrict__ ubf,
    const __hip_bfloat16* __restrict__ wbf, float* __restrict__ zx)
{
    __shared__ __align__(16) short Abuf[64][136];
    __shared__ __align__(16) short Wbuf[80][136];
    const int tid = threadIdx.x;
    const int m0 = blockIdx.x*64;
    const int n0 = blockIdx.y*80;
    for (int i = tid; i < 64*16; i += 256) {
        int r = i >> 4, s = i & 15;
        *(uint4*)&Abuf[r][s*8] = *(const uint4*)&ubf[(size_t)(m0+r)*DM + s*8];
    }
    for (int i = tid; i < 80*16; i += 256) {
        int r = i >> 4, s = i & 15;
        *(uint4*)&Wbuf[r][s*8] = *(const uint4*)&wbf[(size_t)(n0+r)*DM + s*8];
    }
    __syncthreads();
    const int lane = tid & 63, wv = tid >> 6, fr = lane & 15, q = lane >> 4;
    f32x4 acc[5];
    #pragma unroll
    for (int i = 0; i < 5; ++i) acc[i] = (f32x4){0.f,0.f,0.f,0.f};
    #pragma unroll
    for (int kt = 0; kt < 4; ++kt) {
        short8 af = *reinterpret_cast<const short8*>(&Abuf[wv*16 + fr][kt*32 + q*8]);
        #pragma unroll
        for (int ns = 0; ns < 5; ++ns) {
            short8 bf = *reinterpret_cast<const short8*>(&Wbuf[ns*16 + fr][kt*32 + q*8]);
            acc[ns] = __builtin_amdgcn_mfma_f32_16x16x32_bf16(af, bf, acc[ns], 0, 0, 0);
        }
    }
    #pragma unroll
    for (int ns = 0; ns < 5; ++ns) {
        int n = n0 + ns*16 + fr;
        if (n < DPROJ) {
            #pragma unroll
            for (int r = 0; r < 4; ++r)
                zx[(size_t)(m0 + wv*16 + q*4 + r)*DPROJ + n] = acc[ns][r];
        }
    }
}

// ---------------- out-proj MFMA: h = yn(bf16) @ out_w(bf16)^T, K=256 in 2 stages
__global__ __launch_bounds__(256) void k_proj_out(const __hip_bfloat16* __restrict__ ynbf,
    const __hip_bfloat16* __restrict__ wbf, float* __restrict__ h,
    __hip_bfloat16* __restrict__ ubf)
{
    __shared__ __align__(16) short Abuf[64][136];
    __shared__ __align__(16) short Wbuf[128][136];
    const int tid = threadIdx.x;
    const int m0 = blockIdx.x*64;
    const int lane = tid & 63, wv = tid >> 6, fr = lane & 15, q = lane >> 4;
    f32x4 acc[8];
    #pragma unroll
    for (int i = 0; i < 8; ++i) acc[i] = (f32x4){0.f,0.f,0.f,0.f};
    for (int kb = 0; kb < 2; ++kb) {
        if (kb) __syncthreads();
        for (int i = tid; i < 64*16; i += 256) {
            int r = i >> 4, s = i & 15;
            *(uint4*)&Abuf[r][s*8] = *(const uint4*)&ynbf[(size_t)(m0+r)*DIN + kb*128 + s*8];
        }
        for (int i = tid; i < 128*16; i += 256) {
            int r = i >> 4, s = i & 15;
            *(uint4*)&Wbuf[r][s*8] = *(const uint4*)&wbf[(size_t)r*DIN + kb*128 + s*8];
        }
        __syncthreads();
        #pragma unroll
        for (int kt = 0; kt < 4; ++kt) {
            short8 af = *reinterpret_cast<const short8*>(&Abuf[wv*16 + fr][kt*32 + q*8]);
            #pragma unroll
            for (int ns = 0; ns < 8; ++ns) {
                short8 bf = *reinterpret_cast<const short8*>(&Wbuf[ns*16 + fr][kt*32 + q*8]);
                acc[ns] = __builtin_amdgcn_mfma_f32_16x16x32_bf16(af, bf, acc[ns], 0, 0, 0);
            }
        }
    }
    #pragma unroll
    for (int ns = 0; ns < 8; ++ns)
        #pragma unroll
        for (int r = 0; r < 4; ++r) {
            int m = m0 + wv*16 + q*4 + r, n = ns*16 + fr;
            float v = acc[ns][r];
            h[(size_t)m*DM + n] = v;
            ubf[(size_t)m*DM + n] = __float2bfloat16(v);
        }
}

// ---------------- combine xmid/h2 -> Hc bf16
__global__ __launch_bounds__(256) void k_prep_up(const float* __restrict__ xmid,
    const float* __restrict__ h2, const float* __restrict__ gate1,
    __hip_bfloat16* __restrict__ hc)
{
    const float alpha = 1.f / (1.f + expf(-gate1[0]));
    size_t i4 = ((size_t)blockIdx.x*256 + threadIdx.x)*4;
    float4 a = *(const float4*)&xmid[i4];
    float4 b = *(const float4*)&h2[i4];
    float ca = 1.f + alpha, cb = 1.f - alpha;
    uint2 pk;
    pk.x = bfpack2(ca*a.x + cb*b.x, ca*a.y + cb*b.y);
    pk.y = bfpack2(ca*a.z + cb*b.z, ca*a.w + cb*b.w);
    *(uint2*)&hc[i4] = pk;
}

// ---------------- up-proj MFMA + bias + residual + transpose store
__global__ __launch_bounds__(256) void k_up_mfma(const __hip_bfloat16* __restrict__ hc,
    const __hip_bfloat16* __restrict__ wbf, const float* __restrict__ b_up,
    const float* __restrict__ x, float* __restrict__ out)
{
    __shared__ __align__(16) short Abuf[64][136];
    __shared__ __align__(16) short Wbuf[128][136];
    const int tid = threadIdx.x;
    const int m0 = blockIdx.x*64;
    const int n0 = blockIdx.y*128;
    for (int i = tid; i < 64*16; i += 256) {
        int r = i >> 4, s = i & 15;
        *(uint4*)&Abuf[r][s*8] = *(const uint4*)&hc[(size_t)(m0+r)*DM + s*8];
    }
    for (int i = tid; i < 128*16; i += 256) {
        int r = i >> 4, s = i & 15;
        *(uint4*)&Wbuf[r][s*8] = *(const uint4*)&wbf[(size_t)(n0+r)*DM + s*8];
    }
    __syncthreads();
    const int lane = tid & 63, wv = tid >> 6, fr = lane & 15, q = lane >> 4;
    f32x4 acc[8];
    #pragma unroll
    for (int i = 0; i < 8; ++i) acc[i] = (f32x4){0.f,0.f,0.f,0.f};
    #pragma unroll
    for (int kt = 0; kt < 4; ++kt) {
        short8 af = *reinterpret_cast<const short8*>(&Abuf[wv*16 + fr][kt*32 + q*8]);
        #pragma unroll
        for (int ns = 0; ns < 8; ++ns) {
            short8 bf = *reinterpret_cast<const short8*>(&Wbuf[ns*16 + fr][kt*32 + q*8]);
            acc[ns] = __builtin_amdgcn_mfma_f32_16x16x32_bf16(af, bf, acc[ns], 0, 0, 0);
        }
    }
    #pragma unroll
    for (int r = 0; r < 4; ++r) {
        int m = m0 + wv*16 + q*4 + r;
        int b = m >> 11, l = m & 2047;
        size_t rowbase = (size_t)(l*NB + b)*HID + n0;
        #pragma unroll
        for (int ns = 0; ns < 8; ++ns) {
            int n = ns*16 + fr;
            out[rowbase + n] = acc[ns][r] + b_up[n0 + n] + x[rowbase + n];
        }
    }
}

// ---------------- K3: causal depthwise conv7 + bias + silu
__global__ __launch_bounds__(256) void k_conv(const float* __restrict__ zx,
    const float* __restrict__ cw, const float* __restrict__ cb,
    float* __restrict__ xBC)
{
    int idx = blockIdx.x*256 + threadIdx.x;
    if (idx >= MROWS*CONV_DIM) return;
    int c = idx % CONV_DIM;
    int m = idx / CONV_DIM;
    int l = m & 2047, b = m >> 11;
    float acc = cb[c];
    #pragma unroll
    for (int k = 0; k < 7; ++k) {
        int l2 = l - 6 + k;
        if (l2 >= 0)
            acc = fmaf(zx[(size_t)(b*SEQL + l2)*DPROJ + DIN + c], cw[c*7 + k], acc);
    }
    xBC[(size_t)m*CONV_DIM + c] = siluf(acc);
}

// ---------------- K4a: chunk-local scan states
__global__ __launch_bounds__(64) void k_scan_state(const float* __restrict__ zx,
    const float* __restrict__ xBC, const float* __restrict__ dt_bias,
    const float* __restrict__ A_log, float* __restrict__ Sbuf, float* __restrict__ Pbuf)
{
    const int bid = blockIdx.x;
    const int c   = bid & (NCHUNK-1);
    const int h   = (bid >> 5) & (NH-1);
    const int b   = (bid >> 7) & 3;
    const int dir = bid >> 9;
    const int tid = threadIdx.x;
    __shared__ float dA_s[TCH], dt_s[TCH];
    __shared__ float Xs[TCH][HD];
    __shared__ float Bs[TCH][DST];
    {
        const int kk = tid;
        const int l = dir ? (SEQL-1 - (c*TCH + kk)) : (c*TCH + kk);
        float dtraw = zx[(size_t)(b*SEQL + l)*DPROJ + 544 + dir*NH + h] + dt_bias[h];
        float dt = dtraw > 20.f ? dtraw : log1pf(expf(dtraw));
        dt_s[kk] = dt;
        dA_s[kk] = expf(dt * (-expf(A_log[h])));
    }
    __syncthreads();
    for (int i = tid; i < TCH*HD; i += 64) {
        int k2 = i >> 6, p = i & 63;
        int l2 = dir ? (SEQL-1 - (c*TCH + k2)) : (c*TCH + k2);
        Xs[k2][p] = dt_s[k2] * xBC[(size_t)(b*SEQL + l2)*CONV_DIM + h*HD + p];
    }
    for (int i = tid; i < TCH*DST; i += 64) {
        int k2 = i >> 4, n = i & 15;
        int l2 = dir ? (SEQL-1 - (c*TCH + k2)) : (c*TCH + k2);
        Bs[k2][n] = xBC[(size_t)(b*SEQL + l2)*CONV_DIM + DIN + n];
    }
    __syncthreads();
    const int pg = tid >> 2, ng = tid & 3;
    float s[4][4];
    #pragma unroll
    for (int i = 0; i < 4; ++i)
        #pragma unroll
        for (int j = 0; j < 4; ++j) s[i][j] = 0.f;
    for (int k2 = 0; k2 < TCH; ++k2) {
        float dAv = dA_s[k2];
        float4 xv = *(const float4*)&Xs[k2][pg*4];
        float4 bv = *(const float4*)&Bs[k2][ng*4];
        float xa[4] = {xv.x, xv.y, xv.z, xv.w};
        float ba[4] = {bv.x, bv.y, bv.z, bv.w};
        #pragma unroll
        for (int i = 0; i < 4; ++i)
            #pragma unroll
            for (int j = 0; j < 4; ++j)
                s[i][j] = fmaf(dAv, s[i][j], xa[i]*ba[j]);
    }
    size_t sb = (size_t)bid * 1024;
    #pragma unroll
    for (int i = 0; i < 4; ++i) {
        float4 v = {s[i][0], s[i][1], s[i][2], s[i][3]};
        *(float4*)&Sbuf[sb + (size_t)((pg*4+i)*16 + ng*4)] = v;
    }
    if (tid == 0) {
        float P = 1.f;
        for (int k2 = 0; k2 < TCH; ++k2) P *= dA_s[k2];
        Pbuf[bid] = P;
    }
}

// ---------------- K4b: sequential combine of chunk states
__global__ __launch_bounds__(1024) void k_scan_combine(const float* __restrict__ Sbuf,
    const float* __restrict__ Pbuf, float* __restrict__ Hbuf)
{
    const int t = threadIdx.x;
    const size_t base = (size_t)blockIdx.x * NCHUNK;
    float carry = 0.f;
    for (int c = 0; c < NCHUNK; ++c) {
        size_t cb = (base + c) * 1024;
        Hbuf[cb + t] = carry;
        carry = fmaf(Pbuf[base + c], carry, Sbuf[cb + t]);
    }
}

// ---------------- K4c: replay with correct init, emit y
__global__ __launch_bounds__(64) void k_scan_out(const float* __restrict__ zx,
    const float* __restrict__ xBC, const float* __restrict__ dt_bias,
    const float* __restrict__ A_log, const float* __restrict__ Hbuf,
    float* __restrict__ yfw, float* __restrict__ ybw)
{
    const int bid = blockIdx.x;
    const int c   = bid & (NCHUNK-1);
    const int h   = (bid >> 5) & (NH-1);
    const int b   = (bid >> 7) & 3;
    const int dir = bid >> 9;
    const int tid = threadIdx.x;
    __shared__ float dA_s[TCH], dt_s[TCH];
    __shared__ float Xs[TCH][HD];
    __shared__ float Bs[TCH][DST];
    __shared__ float Cs[TCH][DST];
    {
        const int kk = tid;
        const int l = dir ? (SEQL-1 - (c*TCH + kk)) : (c*TCH + kk);
        float dtraw = zx[(size_t)(b*SEQL + l)*DPROJ + 544 + dir*NH + h] + dt_bias[h];
        float dt = dtraw > 20.f ? dtraw : log1pf(expf(dtraw));
        dt_s[kk] = dt;
        dA_s[kk] = expf(dt * (-expf(A_log[h])));
    }
    __syncthreads();
    for (int i = tid; i < TCH*HD; i += 64) {
        int k2 = i >> 6, p = i & 63;
        int l2 = dir ? (SEQL-1 - (c*TCH + k2)) : (c*TCH + k2);
        Xs[k2][p] = dt_s[k2] * xBC[(size_t)(b*SEQL + l2)*CONV_DIM + h*HD + p];
    }
    for (int i = tid; i < TCH*DST; i += 64) {
        int k2 = i >> 4, n = i & 15;
        int l2 = dir ? (SEQL-1 - (c*TCH + k2)) : (c*TCH + k2);
        Bs[k2][n] = xBC[(size_t)(b*SEQL + l2)*CONV_DIM + DIN + n];
        Cs[k2][n] = xBC[(size_t)(b*SEQL + l2)*CONV_DIM + DIN + DST + n];
    }
    __syncthreads();
    const int pg = tid >> 2, ng = tid & 3;
    float s[4][4];
    size_t hb = (size_t)bid * 1024;
    #pragma unroll
    for (int i = 0; i < 4; ++i) {
        float4 v = *(const float4*)&Hbuf[hb + (size_t)((pg*4+i)*16 + ng*4)];
        s[i][0] = v.x; s[i][1] = v.y; s[i][2] = v.z; s[i][3] = v.w;
    }
    float* yout = dir ? ybw : yfw;
    for (int k2 = 0; k2 < TCH; ++k2) {
        float dAv = dA_s[k2];
        float4 xv = *(const float4*)&Xs[k2][pg*4];
        float4 bv = *(const float4*)&Bs[k2][ng*4];
        float4 cv = *(const float4*)&Cs[k2][ng*4];
        float xa[4] = {xv.x, xv.y, xv.z, xv.w};
        float ba[4] = {bv.x, bv.y, bv.z, bv.w};
        float ca[4] = {cv.x, cv.y, cv.z, cv.w};
        float y[4];
        #pragma unroll
        for (int i = 0; i < 4; ++i) {
            #pragma unroll
            for (int j = 0; j < 4; ++j)
                s[i][j] = fmaf(dAv, s[i][j], xa[i]*ba[j]);
            y[i] = s[i][0]*ca[0] + s[i][1]*ca[1] + s[i][2]*ca[2] + s[i][3]*ca[3];
        }
        #pragma unroll
        for (int i = 0; i < 4; ++i) {
            y[i] += __shfl_xor(y[i], 1, 64);
            y[i] += __shfl_xor(y[i], 2, 64);
        }
        if (ng == 0) {
            int l2 = dir ? (SEQL-1 - (c*TCH + k2)) : (c*TCH + k2);
            float4 v = {y[0], y[1], y[2], y[3]};
            *(float4*)&yout[(size_t)(b*SEQL + l2)*DIN + h*HD + pg*4] = v;
        }
    }
}

// ---------------- K5: shift-combine + D-skip + gate + RMSNorm -> yn (bf16)
__global__ __launch_bounds__(256) void k_epi(const float* __restrict__ zx,
    const float* __restrict__ xBC, const float* __restrict__ yfw,
    const float* __restrict__ ybw, const float* __restrict__ fcD_w,
    const float* __restrict__ Dv, const float* __restrict__ norm_w,
    __hip_bfloat16* __restrict__ ynbf)
{
    const int m = blockIdx.x;
    const int l = m & (SEQL-1);
    const int d = threadIdx.x;
    const int lane = d & 63, wave = d >> 6;
    __shared__ float red[4][4];
    __shared__ float redq[4];
    float xs = xBC[(size_t)m*CONV_DIM + d];
    float yv = 0.f;
    if (l > 0)       yv += yfw[(size_t)(m-1)*DIN + d];
    if (l < SEQL-1)  yv += ybw[(size_t)(m+1)*DIN + d];
    float p0 = wave_sum(xs * fcD_w[0*DIN + d]);
    float p1 = wave_sum(xs * fcD_w[1*DIN + d]);
    float p2 = wave_sum(xs * fcD_w[2*DIN + d]);
    float p3 = wave_sum(xs * fcD_w[3*DIN + d]);
    if (lane == 0) { red[wave][0]=p0; red[wave][1]=p1; red[wave][2]=p2; red[wave][3]=p3; }
    __syncthreads();
    const int h = d >> 6;
    float scal = red[0][h] + red[1][h] + red[2][h] + red[3][h] + Dv[h];
    yv = fmaf(xs, scal, yv);
    float z  = zx[(size_t)m*DPROJ + d];
    float yz = yv * siluf(z);
    float q = wave_sum(yz*yz);
    if (lane == 0) redq[wave] = q;
    __syncthreads();
    float ms = (redq[0] + redq[1] + redq[2] + redq[3]) * (1.f/DIN);
    float r = rsqrtf(ms + 1e-5f);
    ynbf[(size_t)m*DIN + d] = __float2bfloat16(yz * r * norm_w[d]);
}

extern "C" void kernel_launch(void* const* d_in, const int* in_sizes, int n_in,
                              void* d_out, int out_size, void* d_ws, size_t ws_size,
                              hipStream_t stream)
{
    const float* x       = (const float*)d_in[0];
    const float* w_down  = (const float*)d_in[1];
    const float* b_down  = (const float*)d_in[2];
    const float* w_up    = (const float*)d_in[3];
    const float* b_up    = (const float*)d_in[4];
    const float* gate1   = (const float*)d_in[5];
    const float* in_w    = (const float*)d_in[6];
    const float* conv_w  = (const float*)d_in[7];
    const float* conv_b  = (const float*)d_in[8];
    const float* dt_bias = (const float*)d_in[9];
    const float* A_log   = (const float*)d_in[10];
    const float* Dv      = (const float*)d_in[11];
    const float* fcD_w   = (const float*)d_in[12];
    const float* norm_w  = (const float*)d_in[13];
    const float* out_w   = (const float*)d_in[14];
    float* out = (float*)d_out;
    float* ws  = (float*)d_ws;

    size_t off = 0;
    float* xmid = ws + off; off += (size_t)MROWS*DM;
    float* h1   = ws + off; off += (size_t)MROWS*DM;
    float* h2   = ws + off; off += (size_t)MROWS*DM;
    float* zx   = ws + off; off += (size_t)MROWS*DPROJ;
    float* xBC  = ws + off; off += (size_t)MROWS*CONV_DIM;
    float* yfw  = ws + off; off += (size_t)MROWS*DIN;
    float* ybw  = ws + off; off += (size_t)MROWS*DIN;
    float* Sbuf = ws + off; off += (size_t)1024*1024;
    float* Pbuf = ws + off; off += 1024;
    float* Hbuf = ws + off; off += (size_t)1024*1024;
    __hip_bfloat16* bfb = (__hip_bfloat16*)(ws + off);
    size_t bo = 0;
    __hip_bfloat16* wd_bf = bfb + bo; bo += 524288;
    __hip_bfloat16* wu_bf = bfb + bo; bo += 524288;
    __hip_bfloat16* wi_bf = bfb + bo; bo += 71680;
    __hip_bfloat16* wo_bf = bfb + bo; bo += 32768;
    __hip_bfloat16* u_bf  = bfb + bo; bo += (size_t)MROWS*DM;
    __hip_bfloat16* yn_bf = bfb + bo; bo += (size_t)MROWS*DIN;
    __hip_bfloat16* hc_bf = bfb + bo; bo += (size_t)MROWS*DM;
    float* partial = zx;   // alias: consumed before zx written

    k_prep_w<<<4504, 256, 0, stream>>>(w_down, w_up, in_w, out_w, wd_bf, wu_bf, wi_bf, wo_bf);

    dim3 gdown(MROWS/64, 2);
    k_down_mfma<<<gdown, 256, 0, stream>>>(x, wd_bf, partial);
    k_down_fix<<<MROWS*DM/1024, 256, 0, stream>>>(partial, b_down, xmid, u_bf);

    for (int pass = 0; pass < 2; ++pass) {
        float* hout = pass ? h2 : h1;
        dim3 gin(MROWS/64, 7);
        k_proj_in<<<gin, 256, 0, stream>>>(u_bf, wi_bf, zx);
        k_conv<<<(MROWS*CONV_DIM)/256, 256, 0, stream>>>(zx, conv_w, conv_b, xBC);
        k_scan_state<<<1024, 64, 0, stream>>>(zx, xBC, dt_bias, A_log, Sbuf, Pbuf);
        k_scan_combine<<<32, 1024, 0, stream>>>(Sbuf, Pbuf, Hbuf);
        k_scan_out<<<1024, 64, 0, stream>>>(zx, xBC, dt_bias, A_log, Hbuf, yfw, ybw);
        k_epi<<<MROWS, 256, 0, stream>>>(zx, xBC, yfw, ybw, fcD_w, Dv, norm_w, yn_bf);
        k_proj_out<<<MROWS/64, 256, 0, stream>>>(yn_bf, wo_bf, hout, u_bf);
    }

    k_prep_up<<<MROWS*DM/1024, 256, 0, stream>>>(xmid, h2, gate1, hc_bf);
    dim3 gup(MROWS/64, HID/128);
    k_up_mfma<<<gup, 256, 0, stream>>>(hc_bf, wu_bf, b_up, x, out);
}